// Round 7
// baseline (747.119 us; speedup 1.0000x reference)
//
#include <hip/hip_runtime.h>
#include <hip/hip_bf16.h>
#include <hip/hip_fp16.h>
#include <math.h>

#define B_    32
#define T_    512
#define D_    512
#define P_    200
#define NP_   8
#define N_TOT 1600
#define NEG_  (-100000.0f)
#define LO_SCALE 2048.0f
#define LO_INV   (1.0f/2048.0f)

typedef __attribute__((ext_vector_type(8))) _Float16 f16x8;
typedef __attribute__((ext_vector_type(4))) _Float16 f16x4;
typedef __attribute__((ext_vector_type(4))) float   f32x4;
typedef unsigned long long u64;

// global -> LDS direct copy, 16B per lane; LDS dest = wave-uniform base + lane*16
#define GLL16(gp, lp) __builtin_amdgcn_global_load_lds( \
    (const __attribute__((address_space(1))) void*)(gp), \
    (__attribute__((address_space(3))) void*)(lp), 16, 0, 0)

__device__ __forceinline__ float wave_reduce_sum(float v) {
#pragma unroll
  for (int off = 32; off; off >>= 1) v += __shfl_xor(v, off, 64);
  return v;
}

// monotone f32 -> u32 order transform and inverse
__device__ __forceinline__ unsigned ordf(float f) {
  unsigned u = __float_as_uint(f);
  return (u & 0x80000000u) ? ~u : (u | 0x80000000u);
}
__device__ __forceinline__ float deco(unsigned o) {
  unsigned u = (o & 0x80000000u) ? (o ^ 0x80000000u) : ~o;
  return __uint_as_float(u);
}
// pack: value-major, inverted key (smaller key wins ties). key = i*512 + t < 4096.
__device__ __forceinline__ u64 packvk(float v, int key) {
  return ((u64)ordf(v) << 32) | (u64)(4095 - key);
}

__global__ void init_slots(u64* s) {
  int i = blockIdx.x * 256 + threadIdx.x;
  if (i < 2 * B_ * P_) s[i] = 0ULL;
}

// ---- normalize x rows; emit fp16 split: xh = f16(x/n), xl = f16((x/n - xh)*2^11) ----
__global__ __launch_bounds__(256) void norm_x_kernel(const float* __restrict__ x,
                                                     _Float16* __restrict__ xh,
                                                     _Float16* __restrict__ xl) {
  int row  = blockIdx.x * 4 + (threadIdx.x >> 6);   // 0..16383
  int lane = threadIdx.x & 63;
  const float* xr = x + (size_t)row * D_;
  float4 v0 = *(const float4*)(xr + lane * 4);
  float4 v1 = *(const float4*)(xr + 256 + lane * 4);
  float s = v0.x*v0.x + v0.y*v0.y + v0.z*v0.z + v0.w*v0.w
          + v1.x*v1.x + v1.y*v1.y + v1.z*v1.z + v1.w*v1.w;
  s = wave_reduce_sum(s);
  float dn = fmaxf(sqrtf(s), 1e-12f);
  float f[8] = {v0.x/dn, v0.y/dn, v0.z/dn, v0.w/dn, v1.x/dn, v1.y/dn, v1.z/dn, v1.w/dn};
  f16x4 h0, h1, l0, l1;
#pragma unroll
  for (int j = 0; j < 4; j++) {
    h0[j] = (_Float16)f[j];
    l0[j] = (_Float16)((f[j] - (float)h0[j]) * LO_SCALE);
    h1[j] = (_Float16)f[4 + j];
    l1[j] = (_Float16)((f[4 + j] - (float)h1[j]) * LO_SCALE);
  }
  size_t base = (size_t)row * D_;
  *(f16x4*)(xh + base + lane * 4)       = h0;
  *(f16x4*)(xh + base + 256 + lane * 4) = h1;
  *(f16x4*)(xl + base + lane * 4)       = l0;
  *(f16x4*)(xl + base + 256 + lane * 4) = l1;
}

// ---- normalize prototypes over d, transpose to [n][d], fp16 split ----
__global__ __launch_bounds__(256) void norm_w_kernel(const float* __restrict__ proto,
                                                     _Float16* __restrict__ wh,
                                                     _Float16* __restrict__ wl) {
  int n    = blockIdx.x * 4 + (threadIdx.x >> 6);   // 0..1599
  int lane = threadIdx.x & 63;
  int p = n >> 3, i = n & 7;
  float v[8];
  float s = 0.f;
#pragma unroll
  for (int k = 0; k < 8; k++) {
    int d = k * 64 + lane;
    v[k] = proto[((size_t)p * D_ + d) * NP_ + i];
    s += v[k] * v[k];
  }
  s = wave_reduce_sum(s);
  float dn = fmaxf(sqrtf(s), 1e-12f);
  size_t base = (size_t)n * D_;
#pragma unroll
  for (int k = 0; k < 8; k++) {
    float f = v[k] / dn;
    _Float16 h = (_Float16)f;
    wh[base + k * 64 + lane] = h;
    wl[base + k * 64 + lane] = (_Float16)((f - (float)h) * LO_SCALE);
  }
}

// ---- fp16-split MFMA GEMM + fused per-(b,p) argmax slots ----
// 128(n) x 128(t) tile, BK=32, single 32 KiB buffer, 2 barriers/K-step
// (restores ~4 blocks/CU implicit cross-block overlap; r6's 64KiB dbuf halved it).
// Fragment-major LDS: linear GLL16 writes == linear 1KB/wave frag reads, 0 conflicts.
__global__ __launch_bounds__(256, 4) void gemm_mfma(
    const _Float16* __restrict__ XH, const _Float16* __restrict__ XL,
    const _Float16* __restrict__ WH, const _Float16* __restrict__ WL,
    const float* __restrict__ tm, float* __restrict__ dist,
    u64* __restrict__ rawslot, u64* __restrict__ qslot) {
  __shared__ _Float16 lds[16384];   // 32 KiB: Ah|Al|Xh|Xl, each 4096
  const int b  = blockIdx.z;
  const int n0 = blockIdx.y * 128;
  const int t0 = blockIdx.x * 128;
  const int tid = threadIdx.x;
  const int w = tid >> 6, l = tid & 63;
  const int fr = l & 15;          // row/col within frag
  const int lk = (l >> 4) * 8;    // k elem offset within BK

  // staging: wave w stages one half of (A or X), hi+lo (8 GLL16 each)
  const _Float16* pHi[4]; const _Float16* pLo[4];
  int dstoff;
  {
    int H = w >> 1;
    if ((w & 1) == 0) {           // waves 0,2: A (prototypes) half H
#pragma unroll
      for (int m = 0; m < 4; m++) {
        int row = n0 + H * 64 + m * 16 + fr;
        if (row > N_TOT - 1) row = N_TOT - 1;     // clamp; stores/slots guarded
        pHi[m] = WH + (size_t)row * D_ + lk;
        pLo[m] = WL + (size_t)row * D_ + lk;
      }
      dstoff = H * 2048;
    } else {                      // waves 1,3: X half H
#pragma unroll
      for (int m = 0; m < 4; m++) {
        int col = t0 + H * 64 + m * 16 + fr;
        pHi[m] = XH + ((size_t)b * T_ + col) * D_ + lk;
        pLo[m] = XL + ((size_t)b * T_ + col) * D_ + lk;
      }
      dstoff = 8192 + H * 2048;
    }
  }

#define STAGE(kk) do { \
    _Float16* dh = &lds[dstoff]; \
    _Float16* dl = dh + 4096; \
    GLL16(pHi[0] + (kk), dh);        GLL16(pHi[1] + (kk), dh + 512); \
    GLL16(pHi[2] + (kk), dh + 1024); GLL16(pHi[3] + (kk), dh + 1536); \
    GLL16(pLo[0] + (kk), dl);        GLL16(pLo[1] + (kk), dl + 512); \
    GLL16(pLo[2] + (kk), dl + 1024); GLL16(pLo[3] + (kk), dl + 1536); \
  } while (0)

  const int aB = (w >> 1) * 2048;         // this wave's A half
  const int xB = 8192 + (w & 1) * 2048;   // this wave's X half

  f32x4 acch[4][4], accc[4][4];
#pragma unroll
  for (int m = 0; m < 4; m++)
#pragma unroll
    for (int n = 0; n < 4; n++) { acch[m][n] = (f32x4)0.0f; accc[m][n] = (f32x4)0.0f; }

  for (int kt = 0; kt < 16; ++kt) {
    STAGE(kt * 32);
    __syncthreads();                      // implicit vmcnt(0): LDS tile ready
    f16x8 ah[4], al[4], bh[4], bl[4];
#pragma unroll
    for (int m = 0; m < 4; m++) {
      ah[m] = *(const f16x8*)&lds[aB + m * 512 + l * 8];
      al[m] = *(const f16x8*)&lds[aB + 4096 + m * 512 + l * 8];
    }
#pragma unroll
    for (int n = 0; n < 4; n++) {
      bh[n] = *(const f16x8*)&lds[xB + n * 512 + l * 8];
      bl[n] = *(const f16x8*)&lds[xB + 4096 + n * 512 + l * 8];
    }
#pragma unroll
    for (int m = 0; m < 4; m++)
#pragma unroll
      for (int n = 0; n < 4; n++) {
        acch[m][n] = __builtin_amdgcn_mfma_f32_16x16x32_f16(ah[m], bh[n], acch[m][n], 0, 0, 0);
        accc[m][n] = __builtin_amdgcn_mfma_f32_16x16x32_f16(ah[m], bl[n], accc[m][n], 0, 0, 0);
        accc[m][n] = __builtin_amdgcn_mfma_f32_16x16x32_f16(al[m], bh[n], accc[m][n], 0, 0, 0);
      }
    __syncthreads();                      // protect buffer before next STAGE
  }

  // epilogue: combine, mask, store, and fused (max,first-key) reduction per p-group.
  // C/D: col = lane&15, row = (lane>>4)*4 + reg
  const int fq = l >> 4;
  u64 pm[4], qm[4];
#pragma unroll
  for (int m = 0; m < 4; m++) { pm[m] = 0ULL; qm[m] = 0ULL; }
#pragma unroll
  for (int n = 0; n < 4; n++) {
    int col = t0 + (w & 1) * 64 + n * 16 + fr;   // global t
    float tmc = tm[b * T_ + col];
#pragma unroll
    for (int m = 0; m < 4; m++) {
      int nb = n0 + (w >> 1) * 64 + m * 16 + fq * 4;
#pragma unroll
      for (int r = 0; r < 4; r++) {
        int nr = nb + r;
        if (nr < N_TOT) {
          float v = acch[m][n][r] + accc[m][n][r] * LO_INV;
          v = v * tmc + (1.0f - tmc) * NEG_;
          dist[((size_t)b * N_TOT + nr) * T_ + col] = v;
          int key = ((fq * 4 + r) & 7) * T_ + col;           // i*512 + t
          u64 pk = packvk(v, key);
          if (pk > pm[m]) pm[m] = pk;
          u64 qk = packvk(v + NEG_, key);                     // f32-quantized fallback
          if (qk > qm[m]) qm[m] = qk;
        }
      }
    }
  }
  // cross-lane: lanes sharing a p-group are the 32-lane halves (h = l>>5)
#pragma unroll
  for (int m = 0; m < 4; m++) {
#pragma unroll
    for (int off = 1; off <= 16; off <<= 1) {
      u64 o1 = __shfl_xor(pm[m], off, 64); if (o1 > pm[m]) pm[m] = o1;
      u64 o2 = __shfl_xor(qm[m], off, 64); if (o2 > qm[m]) qm[m] = o2;
    }
  }
  if ((l & 31) == 0) {
    int h = l >> 5;
#pragma unroll
    for (int m = 0; m < 4; m++) {
      int p = (n0 >> 3) + ((w >> 1) * 8) + m * 2 + h;   // global prototype idx
      if (p < P_) {
        atomicMax(&rawslot[b * P_ + p], pm[m]);
        atomicMax(&qslot[b * P_ + p], qm[m]);
      }
    }
  }
#undef STAGE
}

// ---- greedy selection, one wave per (b,p); slots + window gathers ----
__global__ __launch_bounds__(256) void select_kernel(const float* __restrict__ dist,
                                                     const u64* __restrict__ rawslot,
                                                     const u64* __restrict__ qslot,
                                                     const float* __restrict__ tmg,
                                                     const float* __restrict__ psel,
                                                     float* __restrict__ out) {
  int w = threadIdx.x >> 6, lane = threadIdx.x & 63;
  int pair = blockIdx.x * 4 + w;
  int b = pair / P_, p = pair % P_;
  const float* dbase = dist + ((size_t)b * N_TOT + p * NP_) * T_;

  bool okt = true;
#pragma unroll
  for (int c = 0; c < 8; c++) okt = okt && (tmg[b * T_ + c * 64 + lane] == 1.0f);
  bool tmones = (__ballot(okt) == ~0ULL);

  u64 rs = rawslot[pair], qs = qslot[pair];
  float rv = deco((unsigned)(rs >> 32)); int rkey = 4095 - (int)(rs & 0xFFFFu);
  float qv = deco((unsigned)(qs >> 32)); int qkey = 4095 - (int)(qs & 0xFFFFu);

  float valh[8]; int evh[8], sidh[8];
#pragma unroll
  for (int k = 0; k < 8; k++) { valh[k] = 0.f; evh[k] = -1; sidh[k] = 0; }
  unsigned msub = 0xFFu;
  int e_last = 0;

  for (int it = 0; it < 8; ++it) {
    float bv; int bkey;
    if (tmones) {
      if (it == 0) { bv = rv; bkey = rkey; }
      else {
        // window: it==1: e0-3..e0+3 (7 slots); it>=2: (e,e+3] (3 slots). lane = i*8+widx
        int i = lane >> 3, widx = lane & 7;
        int tw, nw;
        if (it == 1) { tw = e_last - 3 + widx; nw = 7; }
        else         { tw = e_last + 1 + widx; nw = 3; }
        bool valid = (widx < nw) && (tw >= 0) && (tw < T_) && (((msub >> i) & 1u) != 0u);
#pragma unroll
        for (int k = 0; k < 8; k++) if (tw == evh[k]) valid = false;
        float v  = valid ? dbase[(size_t)i * T_ + tw] : -3.0e38f;
        int  key = valid ? (i * T_ + tw) : 0x7FFFFFFF;
#pragma unroll
        for (int off = 32; off; off >>= 1) {
          float ov = __shfl_xor(v, off, 64);
          int  ok2 = __shfl_xor(key, off, 64);
          if (ov > v || (ov == v && ok2 < key)) { v = ov; key = ok2; }
        }
        if (v > -2.9e38f) { bv = v; bkey = key; }
        else              { bv = qv; bkey = qkey; }   // empty window -> uniform +NEG argmax
      }
    } else {
      // general path (mask not all ones): full re-scan with exact ref arithmetic
      float lv = -3.0e38f; int lkey = 0x7FFFFFFF;
      for (int i = 0; i < 8; i++) {
        bool sub_ok = ((msub >> i) & 1u) != 0u;
        const float* row = dbase + (size_t)i * T_;
        float4 u0 = *(const float4*)(row + lane * 8);
        float4 u1 = *(const float4*)(row + lane * 8 + 4);
        float uv[8] = {u0.x, u0.y, u0.z, u0.w, u1.x, u1.y, u1.z, u1.w};
#pragma unroll
        for (int j = 0; j < 8; j++) {
          int t = lane * 8 + j;
          bool act = sub_ok;
          if (it > 0) {
            int dt = t - e_last;
            act = act && (dt <= 3) && (dt >= -3);
            if (it > 1) act = act && (dt > 0);
          }
#pragma unroll
          for (int k = 0; k < 8; k++) if (t == evh[k]) act = false;
          float dm = act ? uv[j] : (uv[j] + NEG_);
          if (dm > lv) { lv = dm; lkey = i * T_ + t; }
        }
      }
#pragma unroll
      for (int off = 32; off; off >>= 1) {
        float ov = __shfl_xor(lv, off, 64);
        int  ok2 = __shfl_xor(lkey, off, 64);
        if (ov > lv || (ov == lv && ok2 < lkey)) { lv = ov; lkey = ok2; }
      }
      bv = lv; bkey = lkey;
    }
    int bi = bkey >> 9, bt = bkey & (T_ - 1);
#pragma unroll
    for (int k = 0; k < 8; k++) {
      if (it == k) { valh[k] = bv; evh[k] = bt; sidh[k] = bi; }
    }
    msub &= ~(1u << bi);
    e_last = bt;
  }

  if (lane == 0) {
    int ord[8]; unsigned used = 0;
#pragma unroll
    for (int j = 0; j < 8; j++) {    // stable argsort of sidh
      int bk = 1 << 30, bi2 = 0;
#pragma unroll
      for (int k = 0; k < 8; k++)
        if (!((used >> k) & 1u)) { int key = sidh[k] * 8 + k; if (key < bk) { bk = key; bi2 = k; } }
      ord[j] = bi2; used |= 1u << bi2;
    }
    float slots[8]; float ssum = 0.f;
#pragma unroll
    for (int i = 0; i < 8; i++) {
      slots[i] = 1.0f / (1.0f + expf(-psel[p * NP_ + i]));
      ssum += slots[i];
    }
    float fac = ssum + 1e-10f;
    float acc = 0.f;
    float vr[8]; float er[8];
#pragma unroll
    for (int j = 0; j < 8; j++) {
      float vv = 0.f, ee = 0.f;
#pragma unroll
      for (int k = 0; k < 8; k++) if (ord[j] == k) { vv = valh[k]; ee = (float)evh[k]; }
      vr[j] = vv; er[j] = ee;
    }
#pragma unroll
    for (int j = 0; j < 8; j++) acc += vr[j] * (slots[j] * 8.0f / fac);
    int bp = b * P_ + p;
    out[bp] = acc;
    out[B_ * P_ + bp] = 8.0f - acc;
#pragma unroll
    for (int j = 0; j < 8; j++) out[2 * B_ * P_ + bp * 8 + j] = er[j];
  }
}

extern "C" void kernel_launch(void* const* d_in, const int* in_sizes, int n_in,
                              void* d_out, int out_size, void* d_ws, size_t ws_size,
                              hipStream_t stream) {
  const float* x     = (const float*)d_in[0];
  const float* tm    = (const float*)d_in[1];
  const float* proto = (const float*)d_in[2];
  const float* psel  = (const float*)d_in[3];
  float* out = (float*)d_out;

  char* wsb = (char*)d_ws;
  _Float16* XH = (_Float16*)wsb;                             // 16,777,216 B
  _Float16* XL = (_Float16*)(wsb + 16777216u);               // 16,777,216 B
  _Float16* WH = (_Float16*)(wsb + 2u * 16777216u);          //  1,638,400 B
  _Float16* WL = (_Float16*)(wsb + 2u * 16777216u + 1638400u);
  float*   dist = (float*)(wsb + 2u * 16777216u + 2u * 1638400u);   // 104,857,600 B
  u64*  rawslot = (u64*)(wsb + 141688832u);                  //  51,200 B
  u64*  qslot   = rawslot + B_ * P_;                         //  51,200 B
  // total = 141,791,232 B

  init_slots<<<dim3(50), 256, 0, stream>>>(rawslot);  // zeroes both arrays (contiguous)
  norm_x_kernel<<<dim3(B_ * T_ / 4), 256, 0, stream>>>(x, XH, XL);
  norm_w_kernel<<<dim3(N_TOT / 4), 256, 0, stream>>>(proto, WH, WL);
  gemm_mfma<<<dim3(T_ / 128, (N_TOT + 127) / 128, B_), 256, 0, stream>>>(
      XH, XL, WH, WL, tm, dist, rawslot, qslot);
  select_kernel<<<dim3(B_ * P_ / 4), 256, 0, stream>>>(dist, rawslot, qslot, tm, psel, out);
}

// Round 8
// 265.408 us; speedup vs baseline: 2.8150x; 2.8150x over previous
//
#include <hip/hip_runtime.h>
#include <hip/hip_bf16.h>
#include <hip/hip_fp16.h>
#include <math.h>

#define B_    32
#define T_    512
#define D_    512
#define P_    200
#define NP_   8
#define N_TOT 1600
#define NEG_  (-100000.0f)
#define LO_SCALE 2048.0f
#define LO_INV   (1.0f/2048.0f)

typedef __attribute__((ext_vector_type(8))) _Float16 f16x8;
typedef __attribute__((ext_vector_type(4))) _Float16 f16x4;
typedef __attribute__((ext_vector_type(4))) float   f32x4;
typedef unsigned long long u64;

// global -> LDS direct copy, 16B per lane; LDS dest = wave-uniform base + lane*16
#define GLL16(gp, lp) __builtin_amdgcn_global_load_lds( \
    (const __attribute__((address_space(1))) void*)(gp), \
    (__attribute__((address_space(3))) void*)(lp), 16, 0, 0)

__device__ __forceinline__ float wave_reduce_sum(float v) {
#pragma unroll
  for (int off = 32; off; off >>= 1) v += __shfl_xor(v, off, 64);
  return v;
}

// monotone f32 -> u32 order transform and inverse
__device__ __forceinline__ unsigned ordf(float f) {
  unsigned u = __float_as_uint(f);
  return (u & 0x80000000u) ? ~u : (u | 0x80000000u);
}
__device__ __forceinline__ float deco(unsigned o) {
  unsigned u = (o & 0x80000000u) ? (o ^ 0x80000000u) : ~o;
  return __uint_as_float(u);
}
// pack: value-major, inverted key (smaller key wins ties). key = i*512 + t < 4096.
__device__ __forceinline__ u64 packvk(float v, int key) {
  return ((u64)ordf(v) << 32) | (u64)(4095 - key);
}

__global__ void init_slots(u64* s) {
  int i = blockIdx.x * 256 + threadIdx.x;
  if (i < 2 * B_ * P_) s[i] = 0ULL;
}

// ---- normalize x rows; emit fp16 split: xh = f16(x/n), xl = f16((x/n - xh)*2^11) ----
__global__ __launch_bounds__(256) void norm_x_kernel(const float* __restrict__ x,
                                                     _Float16* __restrict__ xh,
                                                     _Float16* __restrict__ xl) {
  int row  = blockIdx.x * 4 + (threadIdx.x >> 6);   // 0..16383
  int lane = threadIdx.x & 63;
  const float* xr = x + (size_t)row * D_;
  float4 v0 = *(const float4*)(xr + lane * 4);
  float4 v1 = *(const float4*)(xr + 256 + lane * 4);
  float s = v0.x*v0.x + v0.y*v0.y + v0.z*v0.z + v0.w*v0.w
          + v1.x*v1.x + v1.y*v1.y + v1.z*v1.z + v1.w*v1.w;
  s = wave_reduce_sum(s);
  float dn = fmaxf(sqrtf(s), 1e-12f);
  float f[8] = {v0.x/dn, v0.y/dn, v0.z/dn, v0.w/dn, v1.x/dn, v1.y/dn, v1.z/dn, v1.w/dn};
  f16x4 h0, h1, l0, l1;
#pragma unroll
  for (int j = 0; j < 4; j++) {
    h0[j] = (_Float16)f[j];
    l0[j] = (_Float16)((f[j] - (float)h0[j]) * LO_SCALE);
    h1[j] = (_Float16)f[4 + j];
    l1[j] = (_Float16)((f[4 + j] - (float)h1[j]) * LO_SCALE);
  }
  size_t base = (size_t)row * D_;
  *(f16x4*)(xh + base + lane * 4)       = h0;
  *(f16x4*)(xh + base + 256 + lane * 4) = h1;
  *(f16x4*)(xl + base + lane * 4)       = l0;
  *(f16x4*)(xl + base + 256 + lane * 4) = l1;
}

// ---- normalize prototypes over d, transpose to [n][d], fp16 split ----
__global__ __launch_bounds__(256) void norm_w_kernel(const float* __restrict__ proto,
                                                     _Float16* __restrict__ wh,
                                                     _Float16* __restrict__ wl) {
  int n    = blockIdx.x * 4 + (threadIdx.x >> 6);   // 0..1599
  int lane = threadIdx.x & 63;
  int p = n >> 3, i = n & 7;
  float v[8];
  float s = 0.f;
#pragma unroll
  for (int k = 0; k < 8; k++) {
    int d = k * 64 + lane;
    v[k] = proto[((size_t)p * D_ + d) * NP_ + i];
    s += v[k] * v[k];
  }
  s = wave_reduce_sum(s);
  float dn = fmaxf(sqrtf(s), 1e-12f);
  size_t base = (size_t)n * D_;
#pragma unroll
  for (int k = 0; k < 8; k++) {
    float f = v[k] / dn;
    _Float16 h = (_Float16)f;
    wh[base + k * 64 + lane] = h;
    wl[base + k * 64 + lane] = (_Float16)((f - (float)h) * LO_SCALE);
  }
}

// ---- fp16-split MFMA GEMM + fused per-(b,p) argmax slots ----
// 128(n) x 128(t) tile, BK=32, single 32 KiB buffer, 2 barriers/K-step.
// Fragment-major LDS: linear GLL16 writes == linear 1KB/wave frag reads, 0 conflicts.
// launch_bounds (256,2): r7's (256,4) squeezed VGPRs to 64 -> accumulator spill
// -> 2.8 GB scratch traffic. (256,2) restores ~104 VGPR, no spill, 4 blocks/CU.
__global__ __launch_bounds__(256, 2) void gemm_mfma(
    const _Float16* __restrict__ XH, const _Float16* __restrict__ XL,
    const _Float16* __restrict__ WH, const _Float16* __restrict__ WL,
    const float* __restrict__ tm, float* __restrict__ dist,
    u64* __restrict__ rawslot, u64* __restrict__ qslot) {
  __shared__ _Float16 lds[16384];   // 32 KiB: Ah|Al|Xh|Xl, each 4096
  const int b  = blockIdx.z;
  const int n0 = blockIdx.y * 128;
  const int t0 = blockIdx.x * 128;
  const int tid = threadIdx.x;
  const int w = tid >> 6, l = tid & 63;
  const int fr = l & 15;          // row/col within frag
  const int lk = (l >> 4) * 8;    // k elem offset within BK

  // staging: wave w stages one half of (A or X), hi+lo (8 GLL16 each)
  const _Float16* pHi[4]; const _Float16* pLo[4];
  int dstoff;
  {
    int H = w >> 1;
    if ((w & 1) == 0) {           // waves 0,2: A (prototypes) half H
#pragma unroll
      for (int m = 0; m < 4; m++) {
        int row = n0 + H * 64 + m * 16 + fr;
        if (row > N_TOT - 1) row = N_TOT - 1;     // clamp; stores/slots guarded
        pHi[m] = WH + (size_t)row * D_ + lk;
        pLo[m] = WL + (size_t)row * D_ + lk;
      }
      dstoff = H * 2048;
    } else {                      // waves 1,3: X half H
#pragma unroll
      for (int m = 0; m < 4; m++) {
        int col = t0 + H * 64 + m * 16 + fr;
        pHi[m] = XH + ((size_t)b * T_ + col) * D_ + lk;
        pLo[m] = XL + ((size_t)b * T_ + col) * D_ + lk;
      }
      dstoff = 8192 + H * 2048;
    }
  }

#define STAGE(kk) do { \
    _Float16* dh = &lds[dstoff]; \
    _Float16* dl = dh + 4096; \
    GLL16(pHi[0] + (kk), dh);        GLL16(pHi[1] + (kk), dh + 512); \
    GLL16(pHi[2] + (kk), dh + 1024); GLL16(pHi[3] + (kk), dh + 1536); \
    GLL16(pLo[0] + (kk), dl);        GLL16(pLo[1] + (kk), dl + 512); \
    GLL16(pLo[2] + (kk), dl + 1024); GLL16(pLo[3] + (kk), dl + 1536); \
  } while (0)

  const int aB = (w >> 1) * 2048;         // this wave's A half
  const int xB = 8192 + (w & 1) * 2048;   // this wave's X half

  f32x4 acch[4][4], accc[4][4];
#pragma unroll
  for (int m = 0; m < 4; m++)
#pragma unroll
    for (int n = 0; n < 4; n++) { acch[m][n] = (f32x4)0.0f; accc[m][n] = (f32x4)0.0f; }

  for (int kt = 0; kt < 16; ++kt) {
    STAGE(kt * 32);
    __syncthreads();                      // implicit vmcnt(0): LDS tile ready
    f16x8 ah[4], al[4], bh[4], bl[4];
#pragma unroll
    for (int m = 0; m < 4; m++) {
      ah[m] = *(const f16x8*)&lds[aB + m * 512 + l * 8];
      al[m] = *(const f16x8*)&lds[aB + 4096 + m * 512 + l * 8];
    }
#pragma unroll
    for (int n = 0; n < 4; n++) {
      bh[n] = *(const f16x8*)&lds[xB + n * 512 + l * 8];
      bl[n] = *(const f16x8*)&lds[xB + 4096 + n * 512 + l * 8];
    }
#pragma unroll
    for (int m = 0; m < 4; m++)
#pragma unroll
      for (int n = 0; n < 4; n++) {
        acch[m][n] = __builtin_amdgcn_mfma_f32_16x16x32_f16(ah[m], bh[n], acch[m][n], 0, 0, 0);
        accc[m][n] = __builtin_amdgcn_mfma_f32_16x16x32_f16(ah[m], bl[n], accc[m][n], 0, 0, 0);
        accc[m][n] = __builtin_amdgcn_mfma_f32_16x16x32_f16(al[m], bh[n], accc[m][n], 0, 0, 0);
      }
    __syncthreads();                      // protect buffer before next STAGE
  }

  // epilogue: combine, mask, store, and fused (max,first-key) reduction per p-group.
  // C/D: col = lane&15, row = (lane>>4)*4 + reg
  const int fq = l >> 4;
  u64 pm[4], qm[4];
#pragma unroll
  for (int m = 0; m < 4; m++) { pm[m] = 0ULL; qm[m] = 0ULL; }
#pragma unroll
  for (int n = 0; n < 4; n++) {
    int col = t0 + (w & 1) * 64 + n * 16 + fr;   // global t
    float tmc = tm[b * T_ + col];
#pragma unroll
    for (int m = 0; m < 4; m++) {
      int nb = n0 + (w >> 1) * 64 + m * 16 + fq * 4;
#pragma unroll
      for (int r = 0; r < 4; r++) {
        int nr = nb + r;
        if (nr < N_TOT) {
          float v = acch[m][n][r] + accc[m][n][r] * LO_INV;
          v = v * tmc + (1.0f - tmc) * NEG_;
          dist[((size_t)b * N_TOT + nr) * T_ + col] = v;
          int key = ((fq * 4 + r) & 7) * T_ + col;           // i*512 + t
          u64 pk = packvk(v, key);
          if (pk > pm[m]) pm[m] = pk;
          u64 qk = packvk(v + NEG_, key);                     // f32-quantized fallback
          if (qk > qm[m]) qm[m] = qk;
        }
      }
    }
  }
  // cross-lane: lanes sharing a p-group are the 32-lane halves (h = l>>5)
#pragma unroll
  for (int m = 0; m < 4; m++) {
#pragma unroll
    for (int off = 1; off <= 16; off <<= 1) {
      u64 o1 = __shfl_xor(pm[m], off, 64); if (o1 > pm[m]) pm[m] = o1;
      u64 o2 = __shfl_xor(qm[m], off, 64); if (o2 > qm[m]) qm[m] = o2;
    }
  }
  if ((l & 31) == 0) {
    int h = l >> 5;
#pragma unroll
    for (int m = 0; m < 4; m++) {
      int p = (n0 >> 3) + ((w >> 1) * 8) + m * 2 + h;   // global prototype idx
      if (p < P_) {
        atomicMax(&rawslot[b * P_ + p], pm[m]);
        atomicMax(&qslot[b * P_ + p], qm[m]);
      }
    }
  }
#undef STAGE
}

// ---- greedy selection, one wave per (b,p); slots + window gathers ----
__global__ __launch_bounds__(256) void select_kernel(const float* __restrict__ dist,
                                                     const u64* __restrict__ rawslot,
                                                     const u64* __restrict__ qslot,
                                                     const float* __restrict__ tmg,
                                                     const float* __restrict__ psel,
                                                     float* __restrict__ out) {
  int w = threadIdx.x >> 6, lane = threadIdx.x & 63;
  int pair = blockIdx.x * 4 + w;
  int b = pair / P_, p = pair % P_;
  const float* dbase = dist + ((size_t)b * N_TOT + p * NP_) * T_;

  bool okt = true;
#pragma unroll
  for (int c = 0; c < 8; c++) okt = okt && (tmg[b * T_ + c * 64 + lane] == 1.0f);
  bool tmones = (__ballot(okt) == ~0ULL);

  u64 rs = rawslot[pair], qs = qslot[pair];
  float rv = deco((unsigned)(rs >> 32)); int rkey = 4095 - (int)(rs & 0xFFFFu);
  float qv = deco((unsigned)(qs >> 32)); int qkey = 4095 - (int)(qs & 0xFFFFu);

  float valh[8]; int evh[8], sidh[8];
#pragma unroll
  for (int k = 0; k < 8; k++) { valh[k] = 0.f; evh[k] = -1; sidh[k] = 0; }
  unsigned msub = 0xFFu;
  int e_last = 0;

  for (int it = 0; it < 8; ++it) {
    float bv; int bkey;
    if (tmones) {
      if (it == 0) { bv = rv; bkey = rkey; }
      else {
        // window: it==1: e0-3..e0+3 (7 slots); it>=2: (e,e+3] (3 slots). lane = i*8+widx
        int i = lane >> 3, widx = lane & 7;
        int tw, nw;
        if (it == 1) { tw = e_last - 3 + widx; nw = 7; }
        else         { tw = e_last + 1 + widx; nw = 3; }
        bool valid = (widx < nw) && (tw >= 0) && (tw < T_) && (((msub >> i) & 1u) != 0u);
#pragma unroll
        for (int k = 0; k < 8; k++) if (tw == evh[k]) valid = false;
        float v  = valid ? dbase[(size_t)i * T_ + tw] : -3.0e38f;
        int  key = valid ? (i * T_ + tw) : 0x7FFFFFFF;
#pragma unroll
        for (int off = 32; off; off >>= 1) {
          float ov = __shfl_xor(v, off, 64);
          int  ok2 = __shfl_xor(key, off, 64);
          if (ov > v || (ov == v && ok2 < key)) { v = ov; key = ok2; }
        }
        if (v > -2.9e38f) { bv = v; bkey = key; }
        else              { bv = qv; bkey = qkey; }   // empty window -> uniform +NEG argmax
      }
    } else {
      // general path (mask not all ones): full re-scan with exact ref arithmetic
      float lv = -3.0e38f; int lkey = 0x7FFFFFFF;
      for (int i = 0; i < 8; i++) {
        bool sub_ok = ((msub >> i) & 1u) != 0u;
        const float* row = dbase + (size_t)i * T_;
        float4 u0 = *(const float4*)(row + lane * 8);
        float4 u1 = *(const float4*)(row + lane * 8 + 4);
        float uv[8] = {u0.x, u0.y, u0.z, u0.w, u1.x, u1.y, u1.z, u1.w};
#pragma unroll
        for (int j = 0; j < 8; j++) {
          int t = lane * 8 + j;
          bool act = sub_ok;
          if (it > 0) {
            int dt = t - e_last;
            act = act && (dt <= 3) && (dt >= -3);
            if (it > 1) act = act && (dt > 0);
          }
#pragma unroll
          for (int k = 0; k < 8; k++) if (t == evh[k]) act = false;
          float dm = act ? uv[j] : (uv[j] + NEG_);
          if (dm > lv) { lv = dm; lkey = i * T_ + t; }
        }
      }
#pragma unroll
      for (int off = 32; off; off >>= 1) {
        float ov = __shfl_xor(lv, off, 64);
        int  ok2 = __shfl_xor(lkey, off, 64);
        if (ov > lv || (ov == lv && ok2 < lkey)) { lv = ov; lkey = ok2; }
      }
      bv = lv; bkey = lkey;
    }
    int bi = bkey >> 9, bt = bkey & (T_ - 1);
#pragma unroll
    for (int k = 0; k < 8; k++) {
      if (it == k) { valh[k] = bv; evh[k] = bt; sidh[k] = bi; }
    }
    msub &= ~(1u << bi);
    e_last = bt;
  }

  if (lane == 0) {
    int ord[8]; unsigned used = 0;
#pragma unroll
    for (int j = 0; j < 8; j++) {    // stable argsort of sidh
      int bk = 1 << 30, bi2 = 0;
#pragma unroll
      for (int k = 0; k < 8; k++)
        if (!((used >> k) & 1u)) { int key = sidh[k] * 8 + k; if (key < bk) { bk = key; bi2 = k; } }
      ord[j] = bi2; used |= 1u << bi2;
    }
    float slots[8]; float ssum = 0.f;
#pragma unroll
    for (int i = 0; i < 8; i++) {
      slots[i] = 1.0f / (1.0f + expf(-psel[p * NP_ + i]));
      ssum += slots[i];
    }
    float fac = ssum + 1e-10f;
    float acc = 0.f;
    float vr[8]; float er[8];
#pragma unroll
    for (int j = 0; j < 8; j++) {
      float vv = 0.f, ee = 0.f;
#pragma unroll
      for (int k = 0; k < 8; k++) if (ord[j] == k) { vv = valh[k]; ee = (float)evh[k]; }
      vr[j] = vv; er[j] = ee;
    }
#pragma unroll
    for (int j = 0; j < 8; j++) acc += vr[j] * (slots[j] * 8.0f / fac);
    int bp = b * P_ + p;
    out[bp] = acc;
    out[B_ * P_ + bp] = 8.0f - acc;
#pragma unroll
    for (int j = 0; j < 8; j++) out[2 * B_ * P_ + bp * 8 + j] = er[j];
  }
}

extern "C" void kernel_launch(void* const* d_in, const int* in_sizes, int n_in,
                              void* d_out, int out_size, void* d_ws, size_t ws_size,
                              hipStream_t stream) {
  const float* x     = (const float*)d_in[0];
  const float* tm    = (const float*)d_in[1];
  const float* proto = (const float*)d_in[2];
  const float* psel  = (const float*)d_in[3];
  float* out = (float*)d_out;

  char* wsb = (char*)d_ws;
  _Float16* XH = (_Float16*)wsb;                             // 16,777,216 B
  _Float16* XL = (_Float16*)(wsb + 16777216u);               // 16,777,216 B
  _Float16* WH = (_Float16*)(wsb + 2u * 16777216u);          //  1,638,400 B
  _Float16* WL = (_Float16*)(wsb + 2u * 16777216u + 1638400u);
  float*   dist = (float*)(wsb + 2u * 16777216u + 2u * 1638400u);   // 104,857,600 B
  u64*  rawslot = (u64*)(wsb + 141688832u);                  //  51,200 B
  u64*  qslot   = rawslot + B_ * P_;                         //  51,200 B
  // total = 141,791,232 B

  init_slots<<<dim3(50), 256, 0, stream>>>(rawslot);  // zeroes both arrays (contiguous)
  norm_x_kernel<<<dim3(B_ * T_ / 4), 256, 0, stream>>>(x, XH, XL);
  norm_w_kernel<<<dim3(N_TOT / 4), 256, 0, stream>>>(proto, WH, WL);
  gemm_mfma<<<dim3(T_ / 128, (N_TOT + 127) / 128, B_), 256, 0, stream>>>(
      XH, XL, WH, WL, tm, dist, rawslot, qslot);
  select_kernel<<<dim3(B_ * P_ / 4), 256, 0, stream>>>(dist, rawslot, qslot, tm, psel, out);
}

// Round 9
// 231.363 us; speedup vs baseline: 3.2292x; 1.1472x over previous
//
#include <hip/hip_runtime.h>
#include <hip/hip_bf16.h>
#include <hip/hip_fp16.h>
#include <math.h>

#define B_    32
#define T_    512
#define D_    512
#define P_    200
#define NP_   8
#define N_TOT 1600
#define NEG_  (-100000.0f)
#define LO_SCALE 2048.0f
#define LO_INV   (1.0f/2048.0f)

typedef __attribute__((ext_vector_type(8))) _Float16 f16x8;
typedef __attribute__((ext_vector_type(4))) _Float16 f16x4;
typedef __attribute__((ext_vector_type(4))) float   f32x4;
typedef unsigned long long u64;

// global -> LDS direct copy, 16B per lane; LDS dest = wave-uniform base + lane*16
#define GLL16(gp, lp) __builtin_amdgcn_global_load_lds( \
    (const __attribute__((address_space(1))) void*)(gp), \
    (__attribute__((address_space(3))) void*)(lp), 16, 0, 0)

__device__ __forceinline__ float wave_reduce_sum(float v) {
#pragma unroll
  for (int off = 32; off; off >>= 1) v += __shfl_xor(v, off, 64);
  return v;
}

// monotone f32 -> u32 order transform and inverse
__device__ __forceinline__ unsigned ordf(float f) {
  unsigned u = __float_as_uint(f);
  return (u & 0x80000000u) ? ~u : (u | 0x80000000u);
}
__device__ __forceinline__ float deco(unsigned o) {
  unsigned u = (o & 0x80000000u) ? (o ^ 0x80000000u) : ~o;
  return __uint_as_float(u);
}
// pack: value-major, inverted key (smaller key wins ties). key = i*512 + t < 4096.
__device__ __forceinline__ u64 packvk(float v, int key) {
  return ((u64)ordf(v) << 32) | (u64)(4095 - key);
}

// ---- normalize x rows; emit fp16 split: xh = f16(x/n), xl = f16((x/n - xh)*2^11) ----
__global__ __launch_bounds__(256) void norm_x_kernel(const float* __restrict__ x,
                                                     _Float16* __restrict__ xh,
                                                     _Float16* __restrict__ xl) {
  int row  = blockIdx.x * 4 + (threadIdx.x >> 6);   // 0..16383
  int lane = threadIdx.x & 63;
  const float* xr = x + (size_t)row * D_;
  float4 v0 = *(const float4*)(xr + lane * 4);
  float4 v1 = *(const float4*)(xr + 256 + lane * 4);
  float s = v0.x*v0.x + v0.y*v0.y + v0.z*v0.z + v0.w*v0.w
          + v1.x*v1.x + v1.y*v1.y + v1.z*v1.z + v1.w*v1.w;
  s = wave_reduce_sum(s);
  float dn = fmaxf(sqrtf(s), 1e-12f);
  float f[8] = {v0.x/dn, v0.y/dn, v0.z/dn, v0.w/dn, v1.x/dn, v1.y/dn, v1.z/dn, v1.w/dn};
  f16x4 h0, h1, l0, l1;
#pragma unroll
  for (int j = 0; j < 4; j++) {
    h0[j] = (_Float16)f[j];
    l0[j] = (_Float16)((f[j] - (float)h0[j]) * LO_SCALE);
    h1[j] = (_Float16)f[4 + j];
    l1[j] = (_Float16)((f[4 + j] - (float)h1[j]) * LO_SCALE);
  }
  size_t base = (size_t)row * D_;
  *(f16x4*)(xh + base + lane * 4)       = h0;
  *(f16x4*)(xh + base + 256 + lane * 4) = h1;
  *(f16x4*)(xl + base + lane * 4)       = l0;
  *(f16x4*)(xl + base + 256 + lane * 4) = l1;
}

// ---- normalize prototypes over d, transpose to [n][d], fp16 split; block 0 zeroes slots ----
__global__ __launch_bounds__(256) void norm_w_kernel(const float* __restrict__ proto,
                                                     _Float16* __restrict__ wh,
                                                     _Float16* __restrict__ wl,
                                                     u64* __restrict__ slotbuf) {
  if (blockIdx.x == 0) {    // zero raw+q slots (2*B*P u64); completes before gemm in-stream
    for (int i = threadIdx.x; i < 2 * B_ * P_; i += 256) slotbuf[i] = 0ULL;
  }
  int n    = blockIdx.x * 4 + (threadIdx.x >> 6);   // 0..1599
  int lane = threadIdx.x & 63;
  int p = n >> 3, i = n & 7;
  float v[8];
  float s = 0.f;
#pragma unroll
  for (int k = 0; k < 8; k++) {
    int d = k * 64 + lane;
    v[k] = proto[((size_t)p * D_ + d) * NP_ + i];
    s += v[k] * v[k];
  }
  s = wave_reduce_sum(s);
  float dn = fmaxf(sqrtf(s), 1e-12f);
  size_t base = (size_t)n * D_;
#pragma unroll
  for (int k = 0; k < 8; k++) {
    float f = v[k] / dn;
    _Float16 h = (_Float16)f;
    wh[base + k * 64 + lane] = h;
    wl[base + k * 64 + lane] = (_Float16)((f - (float)h) * LO_SCALE);
  }
}

// ---- fp16-split MFMA GEMM + fused per-(b,p) argmax slots ----
// EXACT r5 structure (measured 111us): symmetric chunk staging (each wave stages
// rows [w*32,(w+1)*32) of all 4 arrays), [row][32] row-major LDS, single 32 KiB
// buffer, 2 barriers/K-step, (256,2). The r8 fragment-major restructure measured
// 164us despite 0 bank conflicts -- conflicts are NOT on the 2-phase critical
// path (stage+vmcnt+barrier is); keep the empirically faster shape.
__global__ __launch_bounds__(256, 2) void gemm_mfma(
    const _Float16* __restrict__ XH, const _Float16* __restrict__ XL,
    const _Float16* __restrict__ WH, const _Float16* __restrict__ WL,
    const float* __restrict__ tm, float* __restrict__ dist,
    u64* __restrict__ rawslot, u64* __restrict__ qslot) {
  __shared__ _Float16 lds[4 * 128 * 32];   // 32 KiB: Ah | Al | Xh | Xl, each [128][32]
  const int b  = blockIdx.z;
  const int n0 = blockIdx.y * 128;
  const int t0 = blockIdx.x * 128;
  const int tid = threadIdx.x;
  const int w = tid >> 6, l = tid & 63;

  // staging: per array 512 chunks of 16B; wave w covers chunks (w*2+j)*64 + lane.
  // chunk c -> global row c>>2, k-offset (c&3)*8; LDS elem offset c*8 == [row][32].
  int c0 = (w * 2 + 0) * 64 + l;
  int c1 = (w * 2 + 1) * 64 + l;
  int r0 = c0 >> 2, kc0 = (c0 & 3) * 8;
  int r1 = c1 >> 2, kc1 = (c1 & 3) * 8;
  int an0 = n0 + r0; if (an0 > N_TOT - 1) an0 = N_TOT - 1;   // clamp (stores/slots guarded)
  int an1 = n0 + r1; if (an1 > N_TOT - 1) an1 = N_TOT - 1;
  const _Float16* wh0 = WH + (size_t)an0 * D_ + kc0;
  const _Float16* wh1 = WH + (size_t)an1 * D_ + kc1;
  const _Float16* wl0 = WL + (size_t)an0 * D_ + kc0;
  const _Float16* wl1 = WL + (size_t)an1 * D_ + kc1;
  const _Float16* xh0 = XH + ((size_t)b * T_ + t0 + r0) * D_ + kc0;
  const _Float16* xh1 = XH + ((size_t)b * T_ + t0 + r1) * D_ + kc1;
  const _Float16* xl0 = XL + ((size_t)b * T_ + t0 + r0) * D_ + kc0;
  const _Float16* xl1 = XL + ((size_t)b * T_ + t0 + r1) * D_ + kc1;
  _Float16* ldAh = lds +     0 + (w * 2) * 512;
  _Float16* ldAl = lds +  4096 + (w * 2) * 512;
  _Float16* ldXh = lds +  8192 + (w * 2) * 512;
  _Float16* ldXl = lds + 12288 + (w * 2) * 512;

  const int wn = (w >> 1) * 64, wtf = (w & 1) * 64;
  const int fr = l & 15, fq = l >> 4;

  f32x4 acch[4][4], accc[4][4];
#pragma unroll
  for (int m = 0; m < 4; m++)
#pragma unroll
    for (int n = 0; n < 4; n++) { acch[m][n] = (f32x4)0.0f; accc[m][n] = (f32x4)0.0f; }

  for (int kt = 0; kt < 16; ++kt) {
    const int k0 = kt * 32;
    GLL16(wh0 + k0, ldAh); GLL16(wh1 + k0, ldAh + 512);
    GLL16(wl0 + k0, ldAl); GLL16(wl1 + k0, ldAl + 512);
    GLL16(xh0 + k0, ldXh); GLL16(xh1 + k0, ldXh + 512);
    GLL16(xl0 + k0, ldXl); GLL16(xl1 + k0, ldXl + 512);
    __syncthreads();                      // implicit vmcnt(0): LDS tile ready
    f16x8 ah[4], al[4], bh[4], bl[4];
#pragma unroll
    for (int m = 0; m < 4; m++) {
      int ro = (wn + m * 16 + fr) * 32 + fq * 8;
      ah[m] = *(const f16x8*)&lds[ro];
      al[m] = *(const f16x8*)&lds[4096 + ro];
    }
#pragma unroll
    for (int n = 0; n < 4; n++) {
      int ro = (wtf + n * 16 + fr) * 32 + fq * 8;
      bh[n] = *(const f16x8*)&lds[8192 + ro];
      bl[n] = *(const f16x8*)&lds[12288 + ro];
    }
#pragma unroll
    for (int m = 0; m < 4; m++)
#pragma unroll
      for (int n = 0; n < 4; n++) {
        acch[m][n] = __builtin_amdgcn_mfma_f32_16x16x32_f16(ah[m], bh[n], acch[m][n], 0, 0, 0);
        accc[m][n] = __builtin_amdgcn_mfma_f32_16x16x32_f16(ah[m], bl[n], accc[m][n], 0, 0, 0);
        accc[m][n] = __builtin_amdgcn_mfma_f32_16x16x32_f16(al[m], bh[n], accc[m][n], 0, 0, 0);
      }
    __syncthreads();                      // protect buffer before next STAGE
  }

  // epilogue: combine, mask, store, and fused (max,first-key) reduction per p-group.
  // C/D: col = lane&15, row = (lane>>4)*4 + reg
  u64 pm[4], qm[4];
#pragma unroll
  for (int m = 0; m < 4; m++) { pm[m] = 0ULL; qm[m] = 0ULL; }
#pragma unroll
  for (int n = 0; n < 4; n++) {
    int col = t0 + wtf + n * 16 + fr;   // global t
    float tmc = tm[b * T_ + col];
#pragma unroll
    for (int m = 0; m < 4; m++) {
      int nb = n0 + wn + m * 16 + fq * 4;
#pragma unroll
      for (int r = 0; r < 4; r++) {
        int nr = nb + r;
        if (nr < N_TOT) {
          float v = acch[m][n][r] + accc[m][n][r] * LO_INV;
          v = v * tmc + (1.0f - tmc) * NEG_;
          dist[((size_t)b * N_TOT + nr) * T_ + col] = v;
          int key = ((fq * 4 + r) & 7) * T_ + col;            // i*512 + t
          u64 pk = packvk(v, key);
          if (pk > pm[m]) pm[m] = pk;
          u64 qk = packvk(v + NEG_, key);                     // f32-quantized fallback
          if (qk > qm[m]) qm[m] = qk;
        }
      }
    }
  }
  // cross-lane: lanes 0-31 hold p-group 0 of each m, lanes 32-63 p-group 1
#pragma unroll
  for (int m = 0; m < 4; m++) {
#pragma unroll
    for (int off = 1; off <= 16; off <<= 1) {
      u64 o1 = __shfl_xor(pm[m], off, 64); if (o1 > pm[m]) pm[m] = o1;
      u64 o2 = __shfl_xor(qm[m], off, 64); if (o2 > qm[m]) qm[m] = o2;
    }
  }
  if ((l & 31) == 0) {
    int h = l >> 5;
#pragma unroll
    for (int m = 0; m < 4; m++) {
      int p = (n0 >> 3) + ((w >> 1) * 8) + m * 2 + h;   // global prototype idx
      if (p < P_) {
        atomicMax(&rawslot[b * P_ + p], pm[m]);
        atomicMax(&qslot[b * P_ + p], qm[m]);
      }
    }
  }
}

// ---- greedy selection, one wave per (b,p); slots + window gathers ----
__global__ __launch_bounds__(256) void select_kernel(const float* __restrict__ dist,
                                                     const u64* __restrict__ rawslot,
                                                     const u64* __restrict__ qslot,
                                                     const float* __restrict__ tmg,
                                                     const float* __restrict__ psel,
                                                     float* __restrict__ out) {
  int w = threadIdx.x >> 6, lane = threadIdx.x & 63;
  int pair = blockIdx.x * 4 + w;
  int b = pair / P_, p = pair % P_;
  const float* dbase = dist + ((size_t)b * N_TOT + p * NP_) * T_;

  bool okt = true;
#pragma unroll
  for (int c = 0; c < 8; c++) okt = okt && (tmg[b * T_ + c * 64 + lane] == 1.0f);
  bool tmones = (__ballot(okt) == ~0ULL);

  u64 rs = rawslot[pair], qs = qslot[pair];
  float rv = deco((unsigned)(rs >> 32)); int rkey = 4095 - (int)(rs & 0xFFFFu);
  float qv = deco((unsigned)(qs >> 32)); int qkey = 4095 - (int)(qs & 0xFFFFu);

  float valh[8]; int evh[8], sidh[8];
#pragma unroll
  for (int k = 0; k < 8; k++) { valh[k] = 0.f; evh[k] = -1; sidh[k] = 0; }
  unsigned msub = 0xFFu;
  int e_last = 0;

  for (int it = 0; it < 8; ++it) {
    float bv; int bkey;
    if (tmones) {
      if (it == 0) { bv = rv; bkey = rkey; }
      else {
        // window: it==1: e0-3..e0+3 (7 slots); it>=2: (e,e+3] (3 slots). lane = i*8+widx
        int i = lane >> 3, widx = lane & 7;
        int tw, nw;
        if (it == 1) { tw = e_last - 3 + widx; nw = 7; }
        else         { tw = e_last + 1 + widx; nw = 3; }
        bool valid = (widx < nw) && (tw >= 0) && (tw < T_) && (((msub >> i) & 1u) != 0u);
#pragma unroll
        for (int k = 0; k < 8; k++) if (tw == evh[k]) valid = false;
        float v  = valid ? dbase[(size_t)i * T_ + tw] : -3.0e38f;
        int  key = valid ? (i * T_ + tw) : 0x7FFFFFFF;
#pragma unroll
        for (int off = 32; off; off >>= 1) {
          float ov = __shfl_xor(v, off, 64);
          int  ok2 = __shfl_xor(key, off, 64);
          if (ov > v || (ov == v && ok2 < key)) { v = ov; key = ok2; }
        }
        if (v > -2.9e38f) { bv = v; bkey = key; }
        else              { bv = qv; bkey = qkey; }   // empty window -> uniform +NEG argmax
      }
    } else {
      // general path (mask not all ones): full re-scan with exact ref arithmetic
      float lv = -3.0e38f; int lkey = 0x7FFFFFFF;
      for (int i = 0; i < 8; i++) {
        bool sub_ok = ((msub >> i) & 1u) != 0u;
        const float* row = dbase + (size_t)i * T_;
        float4 u0 = *(const float4*)(row + lane * 8);
        float4 u1 = *(const float4*)(row + lane * 8 + 4);
        float uv[8] = {u0.x, u0.y, u0.z, u0.w, u1.x, u1.y, u1.z, u1.w};
#pragma unroll
        for (int j = 0; j < 8; j++) {
          int t = lane * 8 + j;
          bool act = sub_ok;
          if (it > 0) {
            int dt = t - e_last;
            act = act && (dt <= 3) && (dt >= -3);
            if (it > 1) act = act && (dt > 0);
          }
#pragma unroll
          for (int k = 0; k < 8; k++) if (t == evh[k]) act = false;
          float dm = act ? uv[j] : (uv[j] + NEG_);
          if (dm > lv) { lv = dm; lkey = i * T_ + t; }
        }
      }
#pragma unroll
      for (int off = 32; off; off >>= 1) {
        float ov = __shfl_xor(lv, off, 64);
        int  ok2 = __shfl_xor(lkey, off, 64);
        if (ov > lv || (ov == lv && ok2 < lkey)) { lv = ov; lkey = ok2; }
      }
      bv = lv; bkey = lkey;
    }
    int bi = bkey >> 9, bt = bkey & (T_ - 1);
#pragma unroll
    for (int k = 0; k < 8; k++) {
      if (it == k) { valh[k] = bv; evh[k] = bt; sidh[k] = bi; }
    }
    msub &= ~(1u << bi);
    e_last = bt;
  }

  if (lane == 0) {
    int ord[8]; unsigned used = 0;
#pragma unroll
    for (int j = 0; j < 8; j++) {    // stable argsort of sidh
      int bk = 1 << 30, bi2 = 0;
#pragma unroll
      for (int k = 0; k < 8; k++)
        if (!((used >> k) & 1u)) { int key = sidh[k] * 8 + k; if (key < bk) { bk = key; bi2 = k; } }
      ord[j] = bi2; used |= 1u << bi2;
    }
    float slots[8]; float ssum = 0.f;
#pragma unroll
    for (int i = 0; i < 8; i++) {
      slots[i] = 1.0f / (1.0f + expf(-psel[p * NP_ + i]));
      ssum += slots[i];
    }
    float fac = ssum + 1e-10f;
    float acc = 0.f;
    float vr[8]; float er[8];
#pragma unroll
    for (int j = 0; j < 8; j++) {
      float vv = 0.f, ee = 0.f;
#pragma unroll
      for (int k = 0; k < 8; k++) if (ord[j] == k) { vv = valh[k]; ee = (float)evh[k]; }
      vr[j] = vv; er[j] = ee;
    }
#pragma unroll
    for (int j = 0; j < 8; j++) acc += vr[j] * (slots[j] * 8.0f / fac);
    int bp = b * P_ + p;
    out[bp] = acc;
    out[B_ * P_ + bp] = 8.0f - acc;
#pragma unroll
    for (int j = 0; j < 8; j++) out[2 * B_ * P_ + bp * 8 + j] = er[j];
  }
}

extern "C" void kernel_launch(void* const* d_in, const int* in_sizes, int n_in,
                              void* d_out, int out_size, void* d_ws, size_t ws_size,
                              hipStream_t stream) {
  const float* x     = (const float*)d_in[0];
  const float* tm    = (const float*)d_in[1];
  const float* proto = (const float*)d_in[2];
  const float* psel  = (const float*)d_in[3];
  float* out = (float*)d_out;

  char* wsb = (char*)d_ws;
  _Float16* XH = (_Float16*)wsb;                             // 16,777,216 B
  _Float16* XL = (_Float16*)(wsb + 16777216u);               // 16,777,216 B
  _Float16* WH = (_Float16*)(wsb + 2u * 16777216u);          //  1,638,400 B
  _Float16* WL = (_Float16*)(wsb + 2u * 16777216u + 1638400u);
  float*   dist = (float*)(wsb + 2u * 16777216u + 2u * 1638400u);   // 104,857,600 B
  u64*  rawslot = (u64*)(wsb + 141688832u);                  //  51,200 B
  u64*  qslot   = rawslot + B_ * P_;                         //  51,200 B
  // total = 141,791,232 B

  norm_x_kernel<<<dim3(B_ * T_ / 4), 256, 0, stream>>>(x, XH, XL);
  norm_w_kernel<<<dim3(N_TOT / 4), 256, 0, stream>>>(proto, WH, WL, rawslot);
  gemm_mfma<<<dim3(T_ / 128, (N_TOT + 127) / 128, B_), 256, 0, stream>>>(
      XH, XL, WH, WL, tm, dist, rawslot, qslot);
  select_kernel<<<dim3(B_ * P_ / 4), 256, 0, stream>>>(dist, rawslot, qslot, tm, psel, out);
}